// Round 3
// baseline (607.505 us; speedup 1.0000x reference)
//
#include <hip/hip_runtime.h>

// Problem constants (fixed by the reference)
#define BTOT 4096
#define TB   512      // T
#define BD   8        // D (input dim)
#define BSL  16       // batch rows per block (M of the MFMA tile)

// LDS element-index map (unsigned short elements, 2 B each):
//   A0 parity0 @ el 0,     parity1 @ el 2048   (row stride 104 el = 208 B)
//   A1 parity0 @ el 8192,  parity1 @ el 12288  (row stride 136 el = 272 B)
// Pow2 parity offsets so a single v_xor toggles the ping-pong pointers.
#define A0P1   2048
#define A1P0   8192
#define A1XOR  4096
#define S0     104    // A0 row stride (elements)
#define S1     136    // A1 row stride (elements)
#define LDSEL  16384  // 32 KiB total

typedef __attribute__((ext_vector_type(8))) short  short8;  // 8 bf16 = 4 VGPR (MFMA A/B frag)
typedef __attribute__((ext_vector_type(4))) float  f32x4;   // MFMA C/D frag

static __device__ __forceinline__ unsigned short f2bf(float f) {
    unsigned u = __float_as_uint(f);
    u += 0x7fffu + ((u >> 16) & 1u);        // RNE (weight load only; hot path uses v_cvt_pk)
    return (unsigned short)(u >> 16);
}
static __device__ __forceinline__ float bf2f(unsigned short h) {
    return __uint_as_float(((unsigned)h) << 16);
}
// sigmoid(z) = 1/(1+2^(-z*log2e))  -> mul, exp2, add, rcp (bias already in z via acc init)
static __device__ __forceinline__ float sigm(float x) {
    float e = __builtin_amdgcn_exp2f(-1.44269504f * x);
    return __builtin_amdgcn_rcpf(1.0f + e);
}
// tanh(z) = 1 - 2/(1+2^(2z*log2e)) -> mul, exp2, add, rcp, fma
static __device__ __forceinline__ float tanh_(float x) {
    float e = __builtin_amdgcn_exp2f(2.88539008f * x);
    return 1.0f - 2.0f * __builtin_amdgcn_rcpf(1.0f + e);
}

// Gate math for TWO accumulator rows (R0, R0+1); returns HW-packed bf16 pair.
template<int R0>
static __device__ __forceinline__ unsigned gates2(
    const f32x4 ai, const f32x4 af, const f32x4 ag, const f32x4 ao,
    float& c0, float& c1)
{
    float h0, h1;
    {
        const float iv = sigm(ai[R0]),     fv = sigm(af[R0]);
        const float gv = tanh_(ag[R0]),    ov = sigm(ao[R0]);
        c0 = fv * c0 + iv * gv;
        h0 = ov * tanh_(c0);
    }
    {
        const float iv = sigm(ai[R0 + 1]), fv = sigm(af[R0 + 1]);
        const float gv = tanh_(ag[R0 + 1]), ov = sigm(ao[R0 + 1]);
        c1 = fv * c1 + iv * gv;
        h1 = ov * tanh_(c1);
    }
    unsigned hp;  // gfx950 HW bf16 pack, RNE: lo = h0, hi = h1
    asm("v_cvt_pk_bf16_f32 %0, %1, %2" : "=v"(hp) : "v"(h0), "v"(h1));
    return hp;
}

__global__ __launch_bounds__(1024) void lstm2_fused(
    const float* __restrict__ x,
    const float* __restrict__ Wih0, const float* __restrict__ Whh0,
    const float* __restrict__ bih0, const float* __restrict__ bhh0,
    const float* __restrict__ Wih1, const float* __restrict__ Whh1,
    const float* __restrict__ bih1, const float* __restrict__ bhh1,
    const float* __restrict__ Wfc,  const float* __restrict__ bfc,
    float* __restrict__ out)
{
    __shared__ __align__(16) unsigned short lds16[LDSEL];

    const int tid  = threadIdx.x;
    const int wid  = tid >> 6;           // 16 waves
    const int lane = tid & 63;
    const int q    = lane >> 4;          // quad (k-chunk for A/B frags, row group for C/D)
    const int ln   = lane & 15;          // A row (m) / B col (n) / C col
    const int rb   = blockIdx.x * BSL;

    // waves 0..7 = layer 0, 8..15 = layer 1.
    // Within a layer: g = column slice (16 hidden cols), rh = accumulator row half.
    // The two rh waves compute IDENTICAL MFMAs (MfmaUtil was 18% - redundancy is
    // free) and split the trans-heavy gate math by rows -> 2x waves hide the
    // quarter-rate exp2/rcp issue cycles.
    const bool L1w = (wid >= 8);
    const int  w   = L1w ? (wid - 8) : wid;
    const int  g   = w & 3;
    const int  rh  = w >> 2;             // 0 or 1
    const int  r0  = rh * 2;
    const int  jc  = g * 16 + ln;        // hidden col this lane owns for all 4 gates

    // ---- Weight (B-operand) fragments -> registers, bf16, once ----
    // All loops constant-bound & unrolled: Bf must never be dynamically indexed
    // (round-1 lesson: scratch demotion -> 738 MB HBM traffic).
    short8 Bf[4][4];
    #pragma unroll
    for (int G = 0; G < 4; ++G) {
        const int n = G * 64 + jc;
        #pragma unroll
        for (int ki = 0; ki < 4; ++ki) {
            union { unsigned short u[8]; short8 v; } t;
            #pragma unroll
            for (int j = 0; j < 8; ++j) {
                const int k = ki * 32 + q * 8 + j;
                float wv = 0.0f;
                if (!L1w) {
                    if (ki < 3) {
                        if (k < 64)      wv = Whh0[n * 64 + k];
                        else if (k < 72) wv = Wih0[n * 8 + (k - 64)];
                    }
                } else {
                    if (k < 64)          wv = Wih1[n * 64 + k];
                    else                 wv = Whh1[n * 64 + (k - 64)];
                }
                t.u[j] = f2bf(wv);
            }
            Bf[G][ki] = t.v;
        }
    }
    float bias[4];
    #pragma unroll
    for (int G = 0; G < 4; ++G) {
        const int n = G * 64 + jc;
        bias[G] = L1w ? (bih1[n] + bhh1[n]) : (bih0[n] + bhh0[n]);
    }

    // ---- Zero LDS (h_{-1}=0; pad columns must be exactly 0.0 forever) ----
    {
        unsigned* z = (unsigned*)lds16;
        #pragma unroll
        for (int i = 0; i < 8; ++i) z[tid + i * 1024] = 0;
    }
    __syncthreads();

    const int xrow = g * 4 + (lane >> 1), xh = lane & 1;  // x loader mapping (rh==0 waves)
    // ---- x_0 -> A0 parity0 x-region (cols 64..71) ----
    if (!L1w && rh == 0 && lane < 8) {
        const float4 v = *(const float4*)(x + ((size_t)(rb + xrow) * TB) * BD + xh * 4);
        unsigned p0, p1;
        asm("v_cvt_pk_bf16_f32 %0, %1, %2" : "=v"(p0) : "v"(v.x), "v"(v.y));
        asm("v_cvt_pk_bf16_f32 %0, %1, %2" : "=v"(p1) : "v"(v.z), "v"(v.w));
        *(uint2*)(lds16 + (xrow * S0 + 64 + xh * 4)) = make_uint2(p0, p1);
    }
    __syncthreads();

    // ---- Hoisted ping-pong LDS pointers (element indices), toggled by XOR ----
    int rdA, wrA, wrC = 0, wrX = 0, xrA, xrW;
    if (!L1w) {
        rdA = ln * S0 + q * 8;                        // A0 parity(it&1)
        wrA = A0P1 + (q * 4 + r0) * S0 + jc;          // A0 parity(it+1)
        wrC = A1P0 + (q * 4 + r0) * S1 + jc;          // A1 parity(it&1): h0 copy
        wrX = A0P1 + xrow * S0 + 64 + xh * 4;         // A0 parity(it+1): x_{t+1}
        xrA = A0P1; xrW = A0P1;
    } else {
        rdA = A1P0 + A1XOR + ln * S1 + q * 8;         // A1 parity((it-1)&1) after 1st toggle
        wrA = A1P0 + (q * 4 + r0) * S1 + 64 + jc;     // A1 parity(it&1): h1
        xrA = A1XOR; xrW = A1XOR;
    }

    float cc0 = 0.f, cc1 = 0.f;   // fp32 cell state (2 rows/lane), never rounded

    // Pipeline: interval it: L0 computes step t=it, L1 computes t1=it-1.
    for (int it = 0; it <= TB; ++it) {
        if (!L1w) {
            if (it < TB) {
                float4 xv;
                const bool dox = (rh == 0) && (lane < 8) && (it + 1 < TB);
                if (dox)
                    xv = *(const float4*)(x + ((size_t)(rb + xrow) * TB + (it + 1)) * BD + xh * 4);

                const short8 a0 = *(const short8*)(lds16 + rdA);
                const short8 a1 = *(const short8*)(lds16 + rdA + 32);
                const short8 a2 = *(const short8*)(lds16 + rdA + 64);

                f32x4 ai = {bias[0], bias[0], bias[0], bias[0]};
                f32x4 af = {bias[1], bias[1], bias[1], bias[1]};
                f32x4 ag = {bias[2], bias[2], bias[2], bias[2]};
                f32x4 ao = {bias[3], bias[3], bias[3], bias[3]};
                ai = __builtin_amdgcn_mfma_f32_16x16x32_bf16(a0, Bf[0][0], ai, 0, 0, 0);
                af = __builtin_amdgcn_mfma_f32_16x16x32_bf16(a0, Bf[1][0], af, 0, 0, 0);
                ag = __builtin_amdgcn_mfma_f32_16x16x32_bf16(a0, Bf[2][0], ag, 0, 0, 0);
                ao = __builtin_amdgcn_mfma_f32_16x16x32_bf16(a0, Bf[3][0], ao, 0, 0, 0);
                ai = __builtin_amdgcn_mfma_f32_16x16x32_bf16(a1, Bf[0][1], ai, 0, 0, 0);
                af = __builtin_amdgcn_mfma_f32_16x16x32_bf16(a1, Bf[1][1], af, 0, 0, 0);
                ag = __builtin_amdgcn_mfma_f32_16x16x32_bf16(a1, Bf[2][1], ag, 0, 0, 0);
                ao = __builtin_amdgcn_mfma_f32_16x16x32_bf16(a1, Bf[3][1], ao, 0, 0, 0);
                ai = __builtin_amdgcn_mfma_f32_16x16x32_bf16(a2, Bf[0][2], ai, 0, 0, 0);
                af = __builtin_amdgcn_mfma_f32_16x16x32_bf16(a2, Bf[1][2], af, 0, 0, 0);
                ag = __builtin_amdgcn_mfma_f32_16x16x32_bf16(a2, Bf[2][2], ag, 0, 0, 0);
                ao = __builtin_amdgcn_mfma_f32_16x16x32_bf16(a2, Bf[3][2], ao, 0, 0, 0);

                const unsigned hp = rh ? gates2<2>(ai, af, ag, ao, cc0, cc1)
                                       : gates2<0>(ai, af, ag, ao, cc0, cc1);
                lds16[wrA]      = (unsigned short)hp;          // ds_write_b16
                lds16[wrA + S0] = (unsigned short)(hp >> 16);  // ds_write_b16_d16_hi
                lds16[wrC]      = (unsigned short)hp;
                lds16[wrC + S1] = (unsigned short)(hp >> 16);

                if (dox) {
                    unsigned p0, p1;
                    asm("v_cvt_pk_bf16_f32 %0, %1, %2" : "=v"(p0) : "v"(xv.x), "v"(xv.y));
                    asm("v_cvt_pk_bf16_f32 %0, %1, %2" : "=v"(p1) : "v"(xv.z), "v"(xv.w));
                    *(uint2*)(lds16 + wrX) = make_uint2(p0, p1);
                }
            }
        } else {
            if (it >= 1) {
                const short8 a0 = *(const short8*)(lds16 + rdA);
                const short8 a1 = *(const short8*)(lds16 + rdA + 32);
                const short8 a2 = *(const short8*)(lds16 + rdA + 64);
                const short8 a3 = *(const short8*)(lds16 + rdA + 96);

                f32x4 ai = {bias[0], bias[0], bias[0], bias[0]};
                f32x4 af = {bias[1], bias[1], bias[1], bias[1]};
                f32x4 ag = {bias[2], bias[2], bias[2], bias[2]};
                f32x4 ao = {bias[3], bias[3], bias[3], bias[3]};
                ai = __builtin_amdgcn_mfma_f32_16x16x32_bf16(a0, Bf[0][0], ai, 0, 0, 0);
                af = __builtin_amdgcn_mfma_f32_16x16x32_bf16(a0, Bf[1][0], af, 0, 0, 0);
                ag = __builtin_amdgcn_mfma_f32_16x16x32_bf16(a0, Bf[2][0], ag, 0, 0, 0);
                ao = __builtin_amdgcn_mfma_f32_16x16x32_bf16(a0, Bf[3][0], ao, 0, 0, 0);
                ai = __builtin_amdgcn_mfma_f32_16x16x32_bf16(a1, Bf[0][1], ai, 0, 0, 0);
                af = __builtin_amdgcn_mfma_f32_16x16x32_bf16(a1, Bf[1][1], af, 0, 0, 0);
                ag = __builtin_amdgcn_mfma_f32_16x16x32_bf16(a1, Bf[2][1], ag, 0, 0, 0);
                ao = __builtin_amdgcn_mfma_f32_16x16x32_bf16(a1, Bf[3][1], ao, 0, 0, 0);
                ai = __builtin_amdgcn_mfma_f32_16x16x32_bf16(a2, Bf[0][2], ai, 0, 0, 0);
                af = __builtin_amdgcn_mfma_f32_16x16x32_bf16(a2, Bf[1][2], af, 0, 0, 0);
                ag = __builtin_amdgcn_mfma_f32_16x16x32_bf16(a2, Bf[2][2], ag, 0, 0, 0);
                ao = __builtin_amdgcn_mfma_f32_16x16x32_bf16(a2, Bf[3][2], ao, 0, 0, 0);
                ai = __builtin_amdgcn_mfma_f32_16x16x32_bf16(a3, Bf[0][3], ai, 0, 0, 0);
                af = __builtin_amdgcn_mfma_f32_16x16x32_bf16(a3, Bf[1][3], af, 0, 0, 0);
                ag = __builtin_amdgcn_mfma_f32_16x16x32_bf16(a3, Bf[2][3], ag, 0, 0, 0);
                ao = __builtin_amdgcn_mfma_f32_16x16x32_bf16(a3, Bf[3][3], ao, 0, 0, 0);

                const unsigned hp = rh ? gates2<2>(ai, af, ag, ao, cc0, cc1)
                                       : gates2<0>(ai, af, ag, ao, cc0, cc1);
                lds16[wrA]      = (unsigned short)hp;
                lds16[wrA + S1] = (unsigned short)(hp >> 16);
            }
        }
        __syncthreads();
        rdA ^= xrA; wrA ^= xrW; wrC ^= A1XOR; wrX ^= A0P1;
    }

    // Final FC: h1_{T-1} written at it=512 -> A1 parity 0, cols 64..127
    if (tid < BSL) {
        float s = bfc[0];
        #pragma unroll 8
        for (int j = 0; j < 64; ++j)
            s += bf2f(lds16[A1P0 + tid * S1 + 64 + j]) * Wfc[j];
        out[rb + tid] = s;
    }
}

extern "C" void kernel_launch(void* const* d_in, const int* in_sizes, int n_in,
                              void* d_out, int out_size, void* d_ws, size_t ws_size,
                              hipStream_t stream) {
    const float* x    = (const float*)d_in[0];
    const float* Wih0 = (const float*)d_in[1];
    const float* Whh0 = (const float*)d_in[2];
    const float* bih0 = (const float*)d_in[3];
    const float* bhh0 = (const float*)d_in[4];
    const float* Wih1 = (const float*)d_in[5];
    const float* Whh1 = (const float*)d_in[6];
    const float* bih1 = (const float*)d_in[7];
    const float* bhh1 = (const float*)d_in[8];
    const float* Wfc  = (const float*)d_in[9];
    const float* bfc  = (const float*)d_in[10];
    float* out = (float*)d_out;

    dim3 grid(BTOT / BSL);   // 256 blocks = 1 per CU
    dim3 block(1024);        // 16 waves: (4 col-slices x 2 row-halves) x 2 layers
    lstm2_fused<<<grid, block, 0, stream>>>(x, Wih0, Whh0, bih0, bhh0,
                                            Wih1, Whh1, bih1, bhh1, Wfc, bfc, out);
}

// Round 5
// 604.653 us; speedup vs baseline: 1.0047x; 1.0047x over previous
//
#include <hip/hip_runtime.h>

// Problem constants (fixed by the reference)
#define BTOT 4096
#define TB   512
#define BD   8
#define BSL  16

// LDS element map (uint16 elements, 2 B each). k-major block layout:
//   element (row, k) of an A-tile lives at  blk(k)*128 + row*8 + (k&7),
//   blk = (k>>5)*4 + ((k>>3)&3)  -> a lane's MFMA A-frag (row=ln, k=ki*32+q*8+j)
//   is 16 contiguous bytes => ds_read_b128, banks 2-way (free, m136).
// A0: p*2048 + blk*128 + row*8 + j   blk 0..7 = h0, blk 8 = x, blk 9..11 = zero pad
// A1: 4096 + p*1024 + blk*128 + ...  blk 0..7 = h1 (L1's ki 2,3)
// XB: 6144 + buf*8192 + (t&63)*128 + row*8 + d   (x chunks, bf16, double-buffered)
#define A0TOG  2048
#define A1BASE 4096
#define A1TOG  1024
#define XBASE  6144
#define XTOG   8192
#define NLDS   22528   // 45056 B

typedef __attribute__((ext_vector_type(8))) short  short8;  // MFMA A/B frag (8 bf16)
typedef __attribute__((ext_vector_type(4))) float  f32x4;   // MFMA C/D frag

static __device__ __forceinline__ unsigned short f2bf(float f) {
    unsigned u = __float_as_uint(f);
    u += 0x7fffu + ((u >> 16) & 1u);
    return (unsigned short)(u >> 16);
}
static __device__ __forceinline__ float bf2f(unsigned short h) {
    return __uint_as_float(((unsigned)h) << 16);
}
static __device__ __forceinline__ unsigned pkbf(float a, float b) {
    unsigned r;  // gfx950 HW packed f32->bf16 (RNE). "=v": dest MUST be VGPR
    asm("v_cvt_pk_bf16_f32 %0, %1, %2" : "=v"(r) : "v"(a), "v"(b));
    return r;
}

// 8 reciprocals from ONE v_rcp via product tree (trans is ~16cyc/wave64; mul is 2).
static __device__ __forceinline__ void inv8(const float d[8], float v[8]) {
    const float p0 = d[0]*d[1], p1 = d[2]*d[3], p2 = d[4]*d[5], p3 = d[6]*d[7];
    const float q0 = p0*p1, q1 = p2*p3;
    const float r  = __builtin_amdgcn_rcpf(q0*q1);
    const float iq0 = q1*r,  iq1 = q0*r;
    const float ip0 = p1*iq0, ip1 = p0*iq0, ip2 = p3*iq1, ip3 = p2*iq1;
    v[0]=d[1]*ip0; v[1]=d[0]*ip0; v[2]=d[3]*ip1; v[3]=d[2]*ip1;
    v[4]=d[5]*ip2; v[5]=d[4]*ip2; v[6]=d[7]*ip3; v[7]=d[6]*ip3;
}
static __device__ __forceinline__ void inv4(const float d[4], float v[4]) {
    const float p0 = d[0]*d[1], p1 = d[2]*d[3];
    const float r  = __builtin_amdgcn_rcpf(p0*p1);
    const float ip0 = p1*r, ip1 = p0*r;
    v[0]=d[1]*ip0; v[1]=d[0]*ip0; v[2]=d[3]*ip1; v[3]=d[2]*ip1;
}

// Gate math, 4 rows. Scales are PRE-FOLDED into weights/bias:
//   i,f,o rows scaled by -log2(e)  => gate = 1/(1+exp2(z))
//   g rows scaled by 2*log2(e)     => tanh = (exp2(z)-1)/(exp2(z)+1)
static __device__ __forceinline__ void gates4(
    const f32x4 ai, const f32x4 af, const f32x4 ag, const f32x4 ao,
    float cc[4], unsigned hp[2])
{
    float ei[4], ef[4], eg[4], eo[4];
    #pragma unroll
    for (int r = 0; r < 4; ++r) {
        ei[r] = __builtin_amdgcn_exp2f(ai[r]);
        ef[r] = __builtin_amdgcn_exp2f(af[r]);
        eg[r] = __builtin_amdgcn_exp2f(ag[r]);
        eo[r] = __builtin_amdgcn_exp2f(ao[r]);
    }
    const float d01[8] = {1.f+ei[0],1.f+ef[0],1.f+eg[0],1.f+eo[0],
                          1.f+ei[1],1.f+ef[1],1.f+eg[1],1.f+eo[1]};
    const float d23[8] = {1.f+ei[2],1.f+ef[2],1.f+eg[2],1.f+eo[2],
                          1.f+ei[3],1.f+ef[3],1.f+eg[3],1.f+eo[3]};
    float v01[8], v23[8];
    inv8(d01, v01); inv8(d23, v23);
    const float iv[4] = {v01[0], v01[4], v23[0], v23[4]};
    const float fv[4] = {v01[1], v01[5], v23[1], v23[5]};
    const float gd[4] = {v01[2], v01[6], v23[2], v23[6]};
    const float ov[4] = {v01[3], v01[7], v23[3], v23[7]};
    float nc[4], dc[4];
    #pragma unroll
    for (int r = 0; r < 4; ++r) {
        const float gv = (eg[r] - 1.f) * gd[r];
        cc[r] = fv[r] * cc[r] + iv[r] * gv;
        const float ec = __builtin_amdgcn_exp2f(2.88539008f * cc[r]);
        nc[r] = ec - 1.f; dc[r] = ec + 1.f;
    }
    float id[4];
    inv4(dc, id);
    const float h0 = ov[0]*(nc[0]*id[0]), h1 = ov[1]*(nc[1]*id[1]);
    const float h2 = ov[2]*(nc[2]*id[2]), h3 = ov[3]*(nc[3]*id[3]);
    hp[0] = pkbf(h0, h1); hp[1] = pkbf(h2, h3);
}

// Stage a 64-step x chunk [t0, t0+64) -> bf16 LDS buffer buf=((t0>>6)&1). All 512 threads.
static __device__ __forceinline__ void stage_x(
    unsigned short* lds16, const float* __restrict__ x, int rb, int tid, int t0)
{
    const int buf = (t0 >> 6) & 1;
    const int row = tid >> 5, u = tid & 31;   // 32 threads/row, 16 floats each (2 t x 8 d)
    const float* gp = x + (size_t)(rb + row) * (TB * BD) + t0 * BD + u * 16;
    const float4 v0 = ((const float4*)gp)[0];
    const float4 v1 = ((const float4*)gp)[1];
    const float4 v2 = ((const float4*)gp)[2];
    const float4 v3 = ((const float4*)gp)[3];
    const int el = XBASE + buf * XTOG + (u * 2) * 128 + row * 8;
    uint4 s0, s1;
    s0.x = pkbf(v0.x, v0.y); s0.y = pkbf(v0.z, v0.w);
    s0.z = pkbf(v1.x, v1.y); s0.w = pkbf(v1.z, v1.w);
    s1.x = pkbf(v2.x, v2.y); s1.y = pkbf(v2.z, v2.w);
    s1.z = pkbf(v3.x, v3.y); s1.w = pkbf(v3.z, v3.w);
    *(uint4*)(lds16 + el)       = s0;   // t = t0 + u*2
    *(uint4*)(lds16 + el + 128) = s1;   // t = t0 + u*2 + 1
}

__global__ __launch_bounds__(512, 2) void lstm2_fused(
    const float* __restrict__ x,
    const float* __restrict__ Wih0, const float* __restrict__ Whh0,
    const float* __restrict__ bih0, const float* __restrict__ bhh0,
    const float* __restrict__ Wih1, const float* __restrict__ Whh1,
    const float* __restrict__ bih1, const float* __restrict__ bhh1,
    const float* __restrict__ Wfc,  const float* __restrict__ bfc,
    float* __restrict__ out)
{
    __shared__ __align__(16) unsigned short lds16[NLDS];

    const int tid  = threadIdx.x;
    const int wid  = tid >> 6;           // 8 waves: 0..3 = layer 0, 4..7 = layer 1
    const int lane = tid & 63;
    const int q    = lane >> 4;
    const int ln   = lane & 15;
    const int rb   = blockIdx.x * BSL;

    const bool L1w = (wid >= 4);
    const int  g   = L1w ? (wid - 4) : wid;
    const int  jc  = g * 16 + ln;        // hidden col this lane owns for all 4 gates

    // ---- Weight fragments -> registers, bf16, exp2-scale pre-folded ----
    // Constant-bound unrolled (round-1 lesson: dynamic index => scratch demotion).
    const float SCI = -1.44269504f;      // sigm: 1/(1+exp2(SCI*z))
    const float SCG =  2.88539008f;      // tanh: (exp2(SCG*z)-1)/(exp2(SCG*z)+1)
    short8 Bf[4][4];
    #pragma unroll
    for (int G = 0; G < 4; ++G) {
        const int n = G * 64 + jc;
        const float sc = (G == 2) ? SCG : SCI;
        #pragma unroll
        for (int ki = 0; ki < 4; ++ki) {
            union { unsigned short u[8]; short8 v; } t;
            #pragma unroll
            for (int j = 0; j < 8; ++j) {
                const int k = ki * 32 + q * 8 + j;
                float wv = 0.0f;
                if (!L1w) {
                    if (ki < 3) {
                        if (k < 64)      wv = Whh0[n * 64 + k];
                        else if (k < 72) wv = Wih0[n * 8 + (k - 64)];
                    }
                } else {
                    if (k < 64)          wv = Wih1[n * 64 + k];
                    else                 wv = Whh1[n * 64 + (k - 64)];
                }
                t.u[j] = f2bf(sc * wv);
            }
            Bf[G][ki] = t.v;
        }
    }
    float bias[4];
    #pragma unroll
    for (int G = 0; G < 4; ++G) {
        const int n = G * 64 + jc;
        const float sc = (G == 2) ? SCG : SCI;
        bias[G] = sc * (L1w ? (bih1[n] + bhh1[n]) : (bih0[n] + bhh0[n]));
    }

    // ---- Prologue: zero A0/A1 (h_{-1}=0, pads=0), stage x chunk 0, place x_0 ----
    stage_x(lds16, x, rb, tid, 0);       // loads fly while we zero
    {
        unsigned* z = (unsigned*)lds16;  // first 6144 els = 3072 uints
        #pragma unroll
        for (int i = 0; i < 6; ++i) z[tid + i * 512] = 0;
    }
    __syncthreads();
    if (tid < 16) {                      // x_0 -> A0 parity0 block 8
        const uint4 v = *(const uint4*)(lds16 + XBASE + tid * 8);
        *(uint4*)(lds16 + 8 * 128 + tid * 8) = v;
    }
    __syncthreads();

    // ---- Hoisted ping-pong pointers (element indices), XOR-toggled ----
    const int rbase = q * 128 + ln * 8;                 // A-frag read base
    const int wb    = (jc >> 3) * 128 + q * 32 + (jc & 7);  // h-write base
    int rdA  = rbase;                    // L0: A0 parity it&1
    int wr0  = A0TOG + wb;               // L0: h0 -> A0 parity (it+1)&1
    int rdH0 = rbase;                    // L1: h0 from A0 parity it&1 (after toggles)
    int rdH1 = A1BASE + rbase;           // L1: h1 from A1 parity it&1
    int wrH1 = A1BASE + A1TOG + wb;      // L1: h1 -> A1 parity (it+1)&1
    int xw   = A0TOG + 1024 + lane * 8;  // x_{it+1} -> A0 parity (it+1)&1 block 8

    float cc[4] = {0.f, 0.f, 0.f, 0.f};  // fp32 cell state, never rounded

    for (int it = 0; it <= TB; ++it) {
        if (((it & 63) == 62) && (it + 2 < TB))
            stage_x(lds16, x, rb, tid, it + 2);   // once per 64 steps; latency amortized

        if (!L1w) {
            if (it < TB) {
                // x_{it+1}: tiny LDS->LDS move (wave 0, 16 lanes)
                if (wid == 0 && lane < 16 && it + 1 < TB) {
                    const int tn = it + 1;
                    const int xr = XBASE + ((tn >> 6) & 1) * XTOG + (tn & 63) * 128 + lane * 8;
                    const uint4 v = *(const uint4*)(lds16 + xr);
                    *(uint4*)(lds16 + xw) = v;
                }
                const short8 a0 = *(const short8*)(lds16 + rdA);
                const short8 a1 = *(const short8*)(lds16 + rdA + 512);
                const short8 a2 = *(const short8*)(lds16 + rdA + 1024);

                f32x4 ai = {bias[0], bias[0], bias[0], bias[0]};
                f32x4 af = {bias[1], bias[1], bias[1], bias[1]};
                f32x4 ag = {bias[2], bias[2], bias[2], bias[2]};
                f32x4 ao = {bias[3], bias[3], bias[3], bias[3]};
                ai = __builtin_amdgcn_mfma_f32_16x16x32_bf16(a0, Bf[0][0], ai, 0, 0, 0);
                af = __builtin_amdgcn_mfma_f32_16x16x32_bf16(a0, Bf[1][0], af, 0, 0, 0);
                ag = __builtin_amdgcn_mfma_f32_16x16x32_bf16(a0, Bf[2][0], ag, 0, 0, 0);
                ao = __builtin_amdgcn_mfma_f32_16x16x32_bf16(a0, Bf[3][0], ao, 0, 0, 0);
                ai = __builtin_amdgcn_mfma_f32_16x16x32_bf16(a1, Bf[0][1], ai, 0, 0, 0);
                af = __builtin_amdgcn_mfma_f32_16x16x32_bf16(a1, Bf[1][1], af, 0, 0, 0);
                ag = __builtin_amdgcn_mfma_f32_16x16x32_bf16(a1, Bf[2][1], ag, 0, 0, 0);
                ao = __builtin_amdgcn_mfma_f32_16x16x32_bf16(a1, Bf[3][1], ao, 0, 0, 0);
                ai = __builtin_amdgcn_mfma_f32_16x16x32_bf16(a2, Bf[0][2], ai, 0, 0, 0);
                af = __builtin_amdgcn_mfma_f32_16x16x32_bf16(a2, Bf[1][2], af, 0, 0, 0);
                ag = __builtin_amdgcn_mfma_f32_16x16x32_bf16(a2, Bf[2][2], ag, 0, 0, 0);
                ao = __builtin_amdgcn_mfma_f32_16x16x32_bf16(a2, Bf[3][2], ao, 0, 0, 0);

                unsigned hp[2];
                gates4(ai, af, ag, ao, cc, hp);
                lds16[wr0]           = (unsigned short)hp[0];
                lds16[wr0 + 8]       = (unsigned short)(hp[0] >> 16);
                lds16[wr0 + 16]      = (unsigned short)hp[1];
                lds16[wr0 + 24]      = (unsigned short)(hp[1] >> 16);
            }
        } else {
            if (it >= 1) {
                const short8 a0 = *(const short8*)(lds16 + rdH0);        // h0 k 0..31
                const short8 a1 = *(const short8*)(lds16 + rdH0 + 512);  // h0 k 32..63
                const short8 a2 = *(const short8*)(lds16 + rdH1);        // h1 k 0..31
                const short8 a3 = *(const short8*)(lds16 + rdH1 + 512);  // h1 k 32..63

                f32x4 ai = {bias[0], bias[0], bias[0], bias[0]};
                f32x4 af = {bias[1], bias[1], bias[1], bias[1]};
                f32x4 ag = {bias[2], bias[2], bias[2], bias[2]};
                f32x4 ao = {bias[3], bias[3], bias[3], bias[3]};
                ai = __builtin_amdgcn_mfma_f32_16x16x32_bf16(a0, Bf[0][0], ai, 0, 0, 0);
                af = __builtin_amdgcn_mfma_f32_16x16x32_bf16(a0, Bf[1][0], af, 0, 0, 0);
                ag = __builtin_amdgcn_mfma_f32_16x16x32_bf16(a0, Bf[2][0], ag, 0, 0, 0);
                ao = __builtin_amdgcn_mfma_f32_16x16x32_bf16(a0, Bf[3][0], ao, 0, 0, 0);
                ai = __builtin_amdgcn_mfma_f32_16x16x32_bf16(a1, Bf[0][1], ai, 0, 0, 0);
                af = __builtin_amdgcn_mfma_f32_16x16x32_bf16(a1, Bf[1][1], af, 0, 0, 0);
                ag = __builtin_amdgcn_mfma_f32_16x16x32_bf16(a1, Bf[2][1], ag, 0, 0, 0);
                ao = __builtin_amdgcn_mfma_f32_16x16x32_bf16(a1, Bf[3][1], ao, 0, 0, 0);
                ai = __builtin_amdgcn_mfma_f32_16x16x32_bf16(a2, Bf[0][2], ai, 0, 0, 0);
                af = __builtin_amdgcn_mfma_f32_16x16x32_bf16(a2, Bf[1][2], af, 0, 0, 0);
                ag = __builtin_amdgcn_mfma_f32_16x16x32_bf16(a2, Bf[2][2], ag, 0, 0, 0);
                ao = __builtin_amdgcn_mfma_f32_16x16x32_bf16(a2, Bf[3][2], ao, 0, 0, 0);
                ai = __builtin_amdgcn_mfma_f32_16x16x32_bf16(a3, Bf[0][3], ai, 0, 0, 0);
                af = __builtin_amdgcn_mfma_f32_16x16x32_bf16(a3, Bf[1][3], af, 0, 0, 0);
                ag = __builtin_amdgcn_mfma_f32_16x16x32_bf16(a3, Bf[2][3], ag, 0, 0, 0);
                ao = __builtin_amdgcn_mfma_f32_16x16x32_bf16(a3, Bf[3][3], ao, 0, 0, 0);

                unsigned hp[2];
                gates4(ai, af, ag, ao, cc, hp);
                lds16[wrH1]          = (unsigned short)hp[0];
                lds16[wrH1 + 8]      = (unsigned short)(hp[0] >> 16);
                lds16[wrH1 + 16]     = (unsigned short)hp[1];
                lds16[wrH1 + 24]     = (unsigned short)(hp[1] >> 16);
            }
        }
        __syncthreads();
        rdA ^= A0TOG; wr0 ^= A0TOG; rdH0 ^= A0TOG; xw ^= A0TOG;
        rdH1 ^= A1TOG; wrH1 ^= A1TOG;
    }

    // Final FC: h1_{511} lives in A1 parity 1
    if (tid < BSL) {
        float s = bfc[0];
        #pragma unroll 8
        for (int j = 0; j < 64; ++j)
            s += bf2f(lds16[A1BASE + A1TOG + (j >> 3) * 128 + tid * 8 + (j & 7)]) * Wfc[j];
        out[rb + tid] = s;
    }
}

extern "C" void kernel_launch(void* const* d_in, const int* in_sizes, int n_in,
                              void* d_out, int out_size, void* d_ws, size_t ws_size,
                              hipStream_t stream) {
    const float* x    = (const float*)d_in[0];
    const float* Wih0 = (const float*)d_in[1];
    const float* Whh0 = (const float*)d_in[2];
    const float* bih0 = (const float*)d_in[3];
    const float* bhh0 = (const float*)d_in[4];
    const float* Wih1 = (const float*)d_in[5];
    const float* Whh1 = (const float*)d_in[6];
    const float* bih1 = (const float*)d_in[7];
    const float* bhh1 = (const float*)d_in[8];
    const float* Wfc  = (const float*)d_in[9];
    const float* bfc  = (const float*)d_in[10];
    float* out = (float*)d_out;

    dim3 grid(BTOT / BSL);   // 256 blocks = 1 per CU
    dim3 block(512);         // 8 waves: 4 layer-0 + 4 layer-1 (pipelined)
    lstm2_fused<<<grid, block, 0, stream>>>(x, Wih0, Whh0, bih0, bhh0,
                                            Wih1, Whh1, bih1, bhh1, Wfc, bfc, out);
}